// Round 6
// baseline (168.765 us; speedup 1.0000x reference)
//
#include <hip/hip_runtime.h>

#define FFT_N 4096
#define NT    256
// additive skew: affine in all access strides (1/16/256) -> base + imm offsets
#define SK(i) ((i) + ((i) >> 4) + 2 * ((i) >> 8))

__device__ __forceinline__ float2 cadd(float2 a, float2 b) { return make_float2(a.x + b.x, a.y + b.y); }
__device__ __forceinline__ float2 csub(float2 a, float2 b) { return make_float2(a.x - b.x, a.y - b.y); }
__device__ __forceinline__ float2 cmul(float2 a, float2 b) {
    return make_float2(a.x * b.x - a.y * b.y, a.x * b.y + a.y * b.x);
}
__device__ __forceinline__ float2 cmulc(float2 a, float2 b) {  // a * conj(b)
    return make_float2(a.x * b.x + a.y * b.y, a.y * b.x - a.x * b.y);
}

// digit-reverse permutation for base-4 pairs: involution P(P(m)) = m
#define PM(m) ((((m) & 3) << 2) | ((m) >> 2))

// In-place 16-point DFT via two radix-4 layers. Output (PERMIN=false) or input
// (PERMIN=true) is P-permuted: slot m <-> index P(m). SGN=-1 fwd, +1 inv (unnorm).
template <int SGN, bool PERMIN>
__device__ __forceinline__ void ip16(float2* x) {
    const float S = (float)SGN;
    const float C1 = 0.92387953251128675613f;   // cos(pi/8)
    const float S1 = 0.38268343236508977173f;   // sin(pi/8)
    const float R2 = 0.70710678118654752440f;   // sqrt(2)/2
#define BF4(i0, i1, i2, i3) do { \
        float2 x0 = x[i0], x1 = x[i1], x2 = x[i2], x3 = x[i3]; \
        float2 t0 = cadd(x0, x2), t1 = csub(x0, x2); \
        float2 t2 = cadd(x1, x3), t3 = csub(x1, x3); \
        float2 it3 = make_float2(-S * t3.y, S * t3.x); \
        x[i0] = cadd(t0, t2); x[i1] = cadd(t1, it3); \
        x[i2] = csub(t0, t2); x[i3] = csub(t1, it3); \
    } while (0)

    if (!PERMIN) { BF4(0, 4, 8, 12); BF4(1, 5, 9, 13); BF4(2, 6, 10, 14); BF4(3, 7, 11, 15); }
    else         { BF4(0, 1, 2, 3);  BF4(4, 5, 6, 7);  BF4(8, 9, 10, 11); BF4(12, 13, 14, 15); }
    // mid twiddles: slot m *= W16^(S * (m&3) * (m>>2))
    const float2 w1 = make_float2(C1, S * S1), w2 = make_float2(R2, S * R2), w3 = make_float2(S1, S * C1);
    const float2 w6 = make_float2(-R2, S * R2), w9 = make_float2(-C1, -S * S1);
    x[5]  = cmul(x[5],  w1);
    x[6]  = cmul(x[6],  w2);
    x[7]  = cmul(x[7],  w3);
    x[9]  = cmul(x[9],  w2);
    { float2 v = x[10]; x[10] = make_float2(-S * v.y, S * v.x); }  // w4 = S*i
    x[11] = cmul(x[11], w6);
    x[13] = cmul(x[13], w3);
    x[14] = cmul(x[14], w6);
    x[15] = cmul(x[15], w9);
    if (!PERMIN) { BF4(0, 1, 2, 3);  BF4(4, 5, 6, 7);  BF4(8, 9, 10, 11); BF4(12, 13, 14, 15); }
    else         { BF4(0, 4, 8, 12); BF4(1, 5, 9, 13); BF4(2, 6, 10, 14); BF4(3, 7, 11, 15); }
#undef BF4
}

// d_ws: twA[4096] = W4096^(t*r) at [r*256+t]; twB[256] = W256^(j*r) at [r*16+j]
__global__ void twiddle_init(float2* __restrict__ twA, float2* __restrict__ twB) {
    int m = blockIdx.x * NT + threadIdx.x;   // 0..4351
    float s, c;
    if (m < 4096) {
        int r = m >> 8, t = m & 255;
        sincosf(-6.28318530717958647692f * (float)(t * r) / 4096.0f, &s, &c);
        twA[m] = make_float2(c, s);
    } else {
        int k = m - 4096;                    // k = r*16 + j
        int r = k >> 4, j = k & 15;
        sincosf(-6.28318530717958647692f * (float)(j * r) / 256.0f, &s, &c);
        twB[k] = make_float2(c, s);
    }
}

__global__ __launch_bounds__(NT)
__attribute__((amdgpu_waves_per_eu(4, 4)))
void circconv4096_kernel(
    const float* __restrict__ A, const float* __restrict__ Bv,
    float* __restrict__ O,
    const float2* __restrict__ twA, const float2* __restrict__ twB)
{
    __shared__ float2 Z[4381];  // SK(4095)+1 = 35 KB -> 4 blocks/CU (LDS-limited)
    const int t = threadIdx.x;
    const size_t row = blockIdx.x;
    const float* a = A + row * FFT_N;
    const float* b = Bv + row * FFT_N;
    float* o = O + row * FFT_N;

    float2 x[16];

    // ---- step 1: coalesced load + fwd stage (stride 256); out slot m = freq P(m) ----
#pragma unroll
    for (int q = 0; q < 16; ++q) {
        int g = t + NT * q;
        x[q] = make_float2(a[g], b[g]);   // z = a + i*b
    }
    ip16<-1, false>(x);
#pragma unroll
    for (int m = 1; m < 16; ++m) x[m] = cmul(x[m], twA[PM(m) * 256 + t]);
#pragma unroll
    for (int m = 0; m < 16; ++m) Z[SK(t + NT * PM(m))] = x[m];
    __syncthreads();

    // ---- step 2: fwd stage (stride 16) ----
    const int base = ((t >> 4) << 8) + (t & 15);
    const int j = t & 15;
    {
#pragma unroll
        for (int q = 0; q < 16; ++q) x[q] = Z[SK(base + 16 * q)];
        ip16<-1, false>(x);
#pragma unroll
        for (int m = 1; m < 16; ++m) x[m] = cmul(x[m], twB[PM(m) * 16 + j]);
#pragma unroll
        for (int m = 0; m < 16; ++m) Z[SK(base + 16 * PM(m))] = x[m];
    }
    __syncthreads();

    // ---- step 3: fwd contiguous + pointwise square + inv contiguous (registers) ----
    {
        const int b3 = t * 16;
#pragma unroll
        for (int q = 0; q < 16; ++q) x[q] = Z[SK(b3 + q)];
        ip16<-1, false>(x);          // spectrum, P-permuted in slots
#pragma unroll
        for (int m = 0; m < 16; ++m) {
            float2 z = x[m];
            x[m] = make_float2(z.x * z.x - z.y * z.y, 2.0f * z.x * z.y);  // Z^2 (pointwise)
        }
        ip16<1, true>(x);            // consumes P-permuted, natural out
#pragma unroll
        for (int q = 0; q < 16; ++q) Z[SK(b3 + q)] = x[q];
    }
    __syncthreads();

    // ---- step 4: inv stage (stride 16): conj twiddle, inverse dft, P-permuted out ----
    {
#pragma unroll
        for (int r = 0; r < 16; ++r) x[r] = Z[SK(base + 16 * r)];
#pragma unroll
        for (int r = 1; r < 16; ++r) x[r] = cmulc(x[r], twB[r * 16 + j]);
        ip16<1, false>(x);
#pragma unroll
        for (int m = 0; m < 16; ++m) Z[SK(base + 16 * PM(m))] = x[m];
    }
    __syncthreads();

    // ---- step 5: inv stage (stride 256) + coalesced store ----
    {
#pragma unroll
        for (int r = 0; r < 16; ++r) x[r] = Z[SK(t + NT * r)];
#pragma unroll
        for (int r = 1; r < 16; ++r) x[r] = cmulc(x[r], twA[r * 256 + t]);
        ip16<1, false>(x);
        // three unnormalized inverse dft16s = x4096; imag-extraction trick = /2
        const float scale = 1.0f / 8192.0f;
#pragma unroll
        for (int m = 0; m < 16; ++m) o[t + NT * PM(m)] = x[m].y * scale;
    }
}

extern "C" void kernel_launch(void* const* d_in, const int* in_sizes, int n_in,
                              void* d_out, int out_size, void* d_ws, size_t ws_size,
                              hipStream_t stream) {
    const float* a = (const float*)d_in[0];
    const float* b = (const float*)d_in[1];
    float* out = (float*)d_out;
    float2* twA = (float2*)d_ws;          // 4096 float2 = 32 KB
    float2* twB = twA + 4096;             // 256 float2 = 2 KB
    const int B = in_sizes[0] / FFT_N;    // 8192 rows

    twiddle_init<<<17, NT, 0, stream>>>(twA, twB);   // 4352 threads
    circconv4096_kernel<<<B, NT, 0, stream>>>(a, b, out, twA, twB);
}

// Round 7
// 154.531 us; speedup vs baseline: 1.0921x; 1.0921x over previous
//
#include <hip/hip_runtime.h>

#define FFT_N 4096
#define NT    512
// skew: +1 float2 per 8 -> contiguous-8 per-thread access lands 4-way, strided ~2-4-way
#define SK(i) ((i) + ((i) >> 3))
// 3-bit reverse (involution): 0,4,2,6,1,5,3,7
#define B3(m) ((((m) & 1) << 2) | ((m) & 2) | ((m) >> 2))

__device__ __forceinline__ float2 cadd(float2 a, float2 b) { return make_float2(a.x + b.x, a.y + b.y); }
__device__ __forceinline__ float2 csub(float2 a, float2 b) { return make_float2(a.x - b.x, a.y - b.y); }
__device__ __forceinline__ float2 cmul(float2 a, float2 b) {
    return make_float2(a.x * b.x - a.y * b.y, a.x * b.y + a.y * b.x);
}
__device__ __forceinline__ float2 cmulc(float2 a, float2 b) {  // a * conj(b)
    return make_float2(a.x * b.x + a.y * b.y, a.y * b.x - a.x * b.y);
}

// In-place 8-point DFT, three radix-2 layers.
// PERMIN=false: natural in, slot m holds freq B3(m) (DIF, twiddle after layer).
// PERMIN=true : slot m holds input B3(m), natural out (DIT, twiddle before layer).
// SGN=-1 fwd, +1 inv (unnormalized). Verified by hand on delta input (both paths).
template <int SGN, bool PERMIN>
__device__ __forceinline__ void ip8(float2* x) {
    const float S = (float)SGN;
    const float R2 = 0.70710678118654752440f;
    const float2 w81 = make_float2(R2, S * R2);    // W8^(S*1)
    const float2 w83 = make_float2(-R2, S * R2);   // W8^(S*3)
#define BF2(i0, i1) { float2 u = x[i0], v = x[i1]; x[i0] = cadd(u, v); x[i1] = csub(u, v); }
#define MSI(i) { float2 v = x[i]; x[i] = make_float2(-S * v.y, S * v.x); }  // *= S*i
    if (!PERMIN) {
        BF2(0, 4) BF2(1, 5) BF2(2, 6) BF2(3, 7)
        x[5] = cmul(x[5], w81); MSI(6) x[7] = cmul(x[7], w83);
        BF2(0, 2) BF2(1, 3) BF2(4, 6) BF2(5, 7)
        MSI(3) MSI(7)
        BF2(0, 1) BF2(2, 3) BF2(4, 5) BF2(6, 7)
    } else {
        BF2(0, 1) BF2(2, 3) BF2(4, 5) BF2(6, 7)
        MSI(3) MSI(7)
        BF2(0, 2) BF2(1, 3) BF2(4, 6) BF2(5, 7)
        x[5] = cmul(x[5], w81); MSI(6) x[7] = cmul(x[7], w83);
        BF2(0, 4) BF2(1, 5) BF2(2, 6) BF2(3, 7)
    }
#undef BF2
#undef MSI
}

// d_ws: twA[4096]=W4096^(t*r) @ [r*512+t]; twB[512]=W512^(j*r) @ [r*64+j];
//       twC[64]=W64^(j*r) @ [r*8+j]
__global__ void twiddle_init(float2* __restrict__ twA, float2* __restrict__ twB,
                             float2* __restrict__ twC) {
    int m = blockIdx.x * NT + threadIdx.x;
    if (m >= 4672) return;
    const float TP = -6.28318530717958647692f;
    float s, c;
    if (m < 4096) {
        int r = m >> 9, t = m & 511;
        sincosf(TP * (float)(t * r) / 4096.0f, &s, &c);
        twA[m] = make_float2(c, s);
    } else if (m < 4608) {
        int k = m - 4096, r = k >> 6, j = k & 63;
        sincosf(TP * (float)(j * r) / 512.0f, &s, &c);
        twB[k] = make_float2(c, s);
    } else {
        int k = m - 4608, r = k >> 3, j = k & 7;
        sincosf(TP * (float)(j * r) / 64.0f, &s, &c);
        twC[k] = make_float2(c, s);
    }
}

__global__ __launch_bounds__(NT) void circconv4096_kernel(
    const float* __restrict__ A, const float* __restrict__ Bv,
    float* __restrict__ O,
    const float2* __restrict__ twA, const float2* __restrict__ twB,
    const float2* __restrict__ twC)
{
    __shared__ float2 Z[SK(4095) + 1];   // 4607 float2 = 36.9 KB -> 4 blocks/CU
    const int t = threadIdx.x;
    const size_t row = blockIdx.x;
    const float* a = A + row * FFT_N;
    const float* b = Bv + row * FFT_N;
    float* o = O + row * FFT_N;

    float2 x[8];

    // ---- fwd stage 1 (stride 512): coalesced load + bf + twiddle ----
#pragma unroll
    for (int q = 0; q < 8; ++q) {
        int g = t + 512 * q;
        x[q] = make_float2(a[g], b[g]);   // z = a + i*b
    }
    ip8<-1, false>(x);
#pragma unroll
    for (int m = 1; m < 8; ++m) x[m] = cmul(x[m], twA[B3(m) * 512 + t]);
#pragma unroll
    for (int m = 0; m < 8; ++m) Z[SK(t + 512 * B3(m))] = x[m];
    __syncthreads();

    // ---- fwd stage 2 (stride 64) ----
    const int j2 = t & 63;
    const int base2 = ((t >> 6) << 9) + j2;
    {
#pragma unroll
        for (int q = 0; q < 8; ++q) x[q] = Z[SK(base2 + 64 * q)];
        ip8<-1, false>(x);
#pragma unroll
        for (int m = 1; m < 8; ++m) x[m] = cmul(x[m], twB[B3(m) * 64 + j2]);
#pragma unroll
        for (int m = 0; m < 8; ++m) Z[SK(base2 + 64 * B3(m))] = x[m];
    }
    __syncthreads();

    // ---- fwd stage 3 (stride 8) ----
    const int j3 = t & 7;
    const int base3 = ((t >> 3) << 6) + j3;
    {
#pragma unroll
        for (int q = 0; q < 8; ++q) x[q] = Z[SK(base3 + 8 * q)];
        ip8<-1, false>(x);
#pragma unroll
        for (int m = 1; m < 8; ++m) x[m] = cmul(x[m], twC[B3(m) * 8 + j3]);
#pragma unroll
        for (int m = 0; m < 8; ++m) Z[SK(base3 + 8 * B3(m))] = x[m];
    }
    __syncthreads();

    // ---- fwd stage 4 (contig) + pointwise square + inv stage 1 (contig), in regs ----
    {
        const int b4 = t * 8;
#pragma unroll
        for (int q = 0; q < 8; ++q) x[q] = Z[SK(b4 + q)];
        ip8<-1, false>(x);           // spectrum, bitrev'd within the 8
#pragma unroll
        for (int m = 0; m < 8; ++m) {
            float2 z = x[m];
            x[m] = make_float2(z.x * z.x - z.y * z.y, 2.0f * z.x * z.y);  // Z^2
        }
        ip8<1, true>(x);             // consumes bitrev'd, natural out
#pragma unroll
        for (int q = 0; q < 8; ++q) Z[SK(b4 + q)] = x[q];
    }
    __syncthreads();

    // ---- inv stage 2 (stride 8): conj twiddle, inverse bf ----
    {
#pragma unroll
        for (int r = 0; r < 8; ++r) x[r] = Z[SK(base3 + 8 * r)];
#pragma unroll
        for (int r = 1; r < 8; ++r) x[r] = cmulc(x[r], twC[r * 8 + j3]);
        ip8<1, false>(x);
#pragma unroll
        for (int m = 0; m < 8; ++m) Z[SK(base3 + 8 * B3(m))] = x[m];
    }
    __syncthreads();

    // ---- inv stage 3 (stride 64) ----
    {
#pragma unroll
        for (int r = 0; r < 8; ++r) x[r] = Z[SK(base2 + 64 * r)];
#pragma unroll
        for (int r = 1; r < 8; ++r) x[r] = cmulc(x[r], twB[r * 64 + j2]);
        ip8<1, false>(x);
#pragma unroll
        for (int m = 0; m < 8; ++m) Z[SK(base2 + 64 * B3(m))] = x[m];
    }
    __syncthreads();

    // ---- inv stage 4 (stride 512) + coalesced store ----
    {
#pragma unroll
        for (int r = 0; r < 8; ++r) x[r] = Z[SK(t + 512 * r)];
#pragma unroll
        for (int r = 1; r < 8; ++r) x[r] = cmulc(x[r], twA[r * 512 + t]);
        ip8<1, false>(x);
        // four unnormalized inverse stages = x4096; imag-extraction trick = /2
        const float scale = 1.0f / 8192.0f;
#pragma unroll
        for (int m = 0; m < 8; ++m) o[t + 512 * B3(m)] = x[m].y * scale;
    }
}

extern "C" void kernel_launch(void* const* d_in, const int* in_sizes, int n_in,
                              void* d_out, int out_size, void* d_ws, size_t ws_size,
                              hipStream_t stream) {
    const float* a = (const float*)d_in[0];
    const float* b = (const float*)d_in[1];
    float* out = (float*)d_out;
    float2* twA = (float2*)d_ws;          // 4096 float2
    float2* twB = twA + 4096;             // 512 float2
    float2* twC = twB + 512;              // 64 float2   (total 37.4 KB)
    const int B = in_sizes[0] / FFT_N;    // 8192 rows

    twiddle_init<<<10, NT, 0, stream>>>(twA, twB, twC);   // 4672 entries
    circconv4096_kernel<<<B, NT, 0, stream>>>(a, b, out, twA, twB, twC);
}

// Round 8
// 154.298 us; speedup vs baseline: 1.0938x; 1.0015x over previous
//
#include <hip/hip_runtime.h>

#define FFT_N 4096
#define NT    512
// skew: +1 float2 per 8
#define SK(i) ((i) + ((i) >> 3))
// 3-bit reverse (involution): 0,4,2,6,1,5,3,7
#define B3(m) ((((m) & 1) << 2) | ((m) & 2) | ((m) >> 2))

__device__ __forceinline__ float2 cadd(float2 a, float2 b) { return make_float2(a.x + b.x, a.y + b.y); }
__device__ __forceinline__ float2 csub(float2 a, float2 b) { return make_float2(a.x - b.x, a.y - b.y); }
__device__ __forceinline__ float2 cmul(float2 a, float2 b) {
    return make_float2(a.x * b.x - a.y * b.y, a.x * b.y + a.y * b.x);
}
__device__ __forceinline__ float2 cmulc(float2 a, float2 b) {  // a * conj(b)
    return make_float2(a.x * b.x + a.y * b.y, a.y * b.x - a.x * b.y);
}

// In-place 8-point DFT, three radix-2 layers (verified r7).
// PERMIN=false: natural in, slot m holds freq B3(m). PERMIN=true: mirrored.
template <int SGN, bool PERMIN>
__device__ __forceinline__ void ip8(float2* x) {
    const float S = (float)SGN;
    const float R2 = 0.70710678118654752440f;
    const float2 w81 = make_float2(R2, S * R2);    // W8^(S*1)
    const float2 w83 = make_float2(-R2, S * R2);   // W8^(S*3)
#define BF2(i0, i1) { float2 u = x[i0], v = x[i1]; x[i0] = cadd(u, v); x[i1] = csub(u, v); }
#define MSI(i) { float2 v = x[i]; x[i] = make_float2(-S * v.y, S * v.x); }  // *= S*i
    if (!PERMIN) {
        BF2(0, 4) BF2(1, 5) BF2(2, 6) BF2(3, 7)
        x[5] = cmul(x[5], w81); MSI(6) x[7] = cmul(x[7], w83);
        BF2(0, 2) BF2(1, 3) BF2(4, 6) BF2(5, 7)
        MSI(3) MSI(7)
        BF2(0, 1) BF2(2, 3) BF2(4, 5) BF2(6, 7)
    } else {
        BF2(0, 1) BF2(2, 3) BF2(4, 5) BF2(6, 7)
        MSI(3) MSI(7)
        BF2(0, 2) BF2(1, 3) BF2(4, 6) BF2(5, 7)
        x[5] = cmul(x[5], w81); MSI(6) x[7] = cmul(x[7], w83);
        BF2(0, 4) BF2(1, 5) BF2(2, 6) BF2(3, 7)
    }
#undef BF2
#undef MSI
}

// d_ws: twA[4096]=W4096^(t*r) @ [r*512+t]; twB[512]=W512^(j*r) @ [r*64+j];
//       twC[64]=W64^(j*r) @ [r*8+j]
__global__ void twiddle_init(float2* __restrict__ twA, float2* __restrict__ twB,
                             float2* __restrict__ twC) {
    int m = blockIdx.x * NT + threadIdx.x;
    if (m >= 4672) return;
    const float TP = -6.28318530717958647692f;
    float s, c;
    if (m < 4096) {
        int r = m >> 9, t = m & 511;
        sincosf(TP * (float)(t * r) / 4096.0f, &s, &c);
        twA[m] = make_float2(c, s);
    } else if (m < 4608) {
        int k = m - 4096, r = k >> 6, j = k & 63;
        sincosf(TP * (float)(j * r) / 512.0f, &s, &c);
        twB[k] = make_float2(c, s);
    } else {
        int k = m - 4608, r = k >> 3, j = k & 7;
        sincosf(TP * (float)(j * r) / 64.0f, &s, &c);
        twC[k] = make_float2(c, s);
    }
}

__global__ __launch_bounds__(NT) void circconv4096_kernel(
    const float* __restrict__ A, const float* __restrict__ Bv,
    float* __restrict__ O,
    const float2* __restrict__ twA, const float2* __restrict__ twB,
    const float2* __restrict__ twC)
{
    __shared__ float2 Z[SK(4095) + 1];   // 4607 float2 = 36.9 KB -> 4 blocks/CU
    const int t = threadIdx.x;
    const size_t row = blockIdx.x;
    const float* a = A + row * FFT_N;
    const float* b = Bv + row * FFT_N;
    float* o = O + row * FFT_N;

    float2 x[8];

    // ---- fwd stage 1 (stride 512): coalesced load + bf + twiddle ----
    // cross-wave exchange -> real barrier after writes
#pragma unroll
    for (int q = 0; q < 8; ++q) {
        int g = t + 512 * q;
        x[q] = make_float2(a[g], b[g]);   // z = a + i*b
    }
    ip8<-1, false>(x);
#pragma unroll
    for (int m = 1; m < 8; ++m) x[m] = cmul(x[m], twA[B3(m) * 512 + t]);
#pragma unroll
    for (int m = 0; m < 8; ++m) Z[SK(t + 512 * B3(m))] = x[m];
    __syncthreads();

    // ---- stages 2..inv3 operate within 512-elem segments owned by one wave ----
    // (wave w = lanes [64w,64w+64) touches only Z[SK(512w)..SK(512w+511)]).
    // Same-wave DS ops complete in order -> compiler fence suffices, no s_barrier.

    // ---- fwd stage 2 (stride 64) ----
    const int j2 = t & 63;
    const int base2 = ((t >> 6) << 9) + j2;
    {
#pragma unroll
        for (int q = 0; q < 8; ++q) x[q] = Z[SK(base2 + 64 * q)];
        ip8<-1, false>(x);
#pragma unroll
        for (int m = 1; m < 8; ++m) x[m] = cmul(x[m], twB[B3(m) * 64 + j2]);
        __builtin_amdgcn_wave_barrier();
#pragma unroll
        for (int m = 0; m < 8; ++m) Z[SK(base2 + 64 * B3(m))] = x[m];
    }
    __builtin_amdgcn_wave_barrier();

    // ---- fwd stage 3 (stride 8) ----
    const int j3 = t & 7;
    const int base3 = ((t >> 3) << 6) + j3;
    {
#pragma unroll
        for (int q = 0; q < 8; ++q) x[q] = Z[SK(base3 + 8 * q)];
        ip8<-1, false>(x);
#pragma unroll
        for (int m = 1; m < 8; ++m) x[m] = cmul(x[m], twC[B3(m) * 8 + j3]);
        __builtin_amdgcn_wave_barrier();
#pragma unroll
        for (int m = 0; m < 8; ++m) Z[SK(base3 + 8 * B3(m))] = x[m];
    }
    __builtin_amdgcn_wave_barrier();

    // ---- fwd stage 4 (contig) + pointwise square + inv stage 1 (contig), in regs ----
    {
        const int b4 = t * 8;
#pragma unroll
        for (int q = 0; q < 8; ++q) x[q] = Z[SK(b4 + q)];
        ip8<-1, false>(x);           // spectrum, bitrev'd within the 8
#pragma unroll
        for (int m = 0; m < 8; ++m) {
            float2 z = x[m];
            x[m] = make_float2(z.x * z.x - z.y * z.y, 2.0f * z.x * z.y);  // Z^2
        }
        ip8<1, true>(x);             // consumes bitrev'd, natural out
        __builtin_amdgcn_wave_barrier();
#pragma unroll
        for (int q = 0; q < 8; ++q) Z[SK(b4 + q)] = x[q];
    }
    __builtin_amdgcn_wave_barrier();

    // ---- inv stage 2 (stride 8): conj twiddle, inverse bf ----
    {
#pragma unroll
        for (int r = 0; r < 8; ++r) x[r] = Z[SK(base3 + 8 * r)];
#pragma unroll
        for (int r = 1; r < 8; ++r) x[r] = cmulc(x[r], twC[r * 8 + j3]);
        ip8<1, false>(x);
        __builtin_amdgcn_wave_barrier();
#pragma unroll
        for (int m = 0; m < 8; ++m) Z[SK(base3 + 8 * B3(m))] = x[m];
    }
    __builtin_amdgcn_wave_barrier();

    // ---- inv stage 3 (stride 64) ----
    {
#pragma unroll
        for (int r = 0; r < 8; ++r) x[r] = Z[SK(base2 + 64 * r)];
#pragma unroll
        for (int r = 1; r < 8; ++r) x[r] = cmulc(x[r], twB[r * 64 + j2]);
        ip8<1, false>(x);
        __builtin_amdgcn_wave_barrier();
#pragma unroll
        for (int m = 0; m < 8; ++m) Z[SK(base2 + 64 * B3(m))] = x[m];
    }
    __syncthreads();   // next stage is stride-512: cross-wave

    // ---- inv stage 4 (stride 512) + coalesced store ----
    {
#pragma unroll
        for (int r = 0; r < 8; ++r) x[r] = Z[SK(t + 512 * r)];
#pragma unroll
        for (int r = 1; r < 8; ++r) x[r] = cmulc(x[r], twA[r * 512 + t]);
        ip8<1, false>(x);
        // four unnormalized inverse stages = x4096; imag-extraction trick = /2
        const float scale = 1.0f / 8192.0f;
#pragma unroll
        for (int m = 0; m < 8; ++m) o[t + 512 * B3(m)] = x[m].y * scale;
    }
}

extern "C" void kernel_launch(void* const* d_in, const int* in_sizes, int n_in,
                              void* d_out, int out_size, void* d_ws, size_t ws_size,
                              hipStream_t stream) {
    const float* a = (const float*)d_in[0];
    const float* b = (const float*)d_in[1];
    float* out = (float*)d_out;
    float2* twA = (float2*)d_ws;          // 4096 float2
    float2* twB = twA + 4096;             // 512 float2
    float2* twC = twB + 512;              // 64 float2   (total 37.4 KB)
    const int B = in_sizes[0] / FFT_N;    // 8192 rows

    twiddle_init<<<10, NT, 0, stream>>>(twA, twB, twC);   // 4672 entries
    circconv4096_kernel<<<B, NT, 0, stream>>>(a, b, out, twA, twB, twC);
}

// Round 9
// 145.010 us; speedup vs baseline: 1.1638x; 1.0640x over previous
//
#include <hip/hip_runtime.h>

#define FFT_N 4096
#define NT    512
// skew: +1 cplx per 8
#define SK(i) ((i) + ((i) >> 3))
// 3-bit reverse (involution): 0,4,2,6,1,5,3,7
#define B3(m) ((((m) & 1) << 2) | ((m) & 2) | ((m) >> 2))

// complex in an even-aligned VGPR pair -> VOP3P packed f32 ops
typedef float cplx __attribute__((ext_vector_type(2)));

__device__ __forceinline__ cplx mkc(float re, float im) { cplx c; c.x = re; c.y = im; return c; }
__device__ __forceinline__ cplx cmul(cplx a, cplx b) {
    return mkc(a.x * b.x - a.y * b.y, a.x * b.y + a.y * b.x);
}
__device__ __forceinline__ cplx cmulc(cplx a, cplx b) {  // a * conj(b)
    return mkc(a.x * b.x + a.y * b.y, a.y * b.x - a.x * b.y);
}

// In-place 8-point DFT, three radix-2 layers (math verified r7/r8).
// PERMIN=false: natural in, slot m holds freq B3(m). PERMIN=true: mirrored.
template <int SGN, bool PERMIN>
__device__ __forceinline__ void ip8(cplx* x) {
    const float S = (float)SGN;
    const float R2 = 0.70710678118654752440f;
    const cplx w81 = mkc(R2, S * R2);    // W8^(S*1)
    const cplx w83 = mkc(-R2, S * R2);   // W8^(S*3)
#define BF2(i0, i1) { cplx u = x[i0], v = x[i1]; x[i0] = u + v; x[i1] = u - v; }
#define MSI(i) { cplx v = x[i]; x[i] = mkc(-S * v.y, S * v.x); }  // *= S*i
    if (!PERMIN) {
        BF2(0, 4) BF2(1, 5) BF2(2, 6) BF2(3, 7)
        x[5] = cmul(x[5], w81); MSI(6) x[7] = cmul(x[7], w83);
        BF2(0, 2) BF2(1, 3) BF2(4, 6) BF2(5, 7)
        MSI(3) MSI(7)
        BF2(0, 1) BF2(2, 3) BF2(4, 5) BF2(6, 7)
    } else {
        BF2(0, 1) BF2(2, 3) BF2(4, 5) BF2(6, 7)
        MSI(3) MSI(7)
        BF2(0, 2) BF2(1, 3) BF2(4, 6) BF2(5, 7)
        x[5] = cmul(x[5], w81); MSI(6) x[7] = cmul(x[7], w83);
        BF2(0, 4) BF2(1, 5) BF2(2, 6) BF2(3, 7)
    }
#undef BF2
#undef MSI
}

// d_ws: twA[4096]=W4096^(t*r) @ [r*512+t]; twB[512]=W512^(j*r) @ [r*64+j];
//       twC[64]=W64^(j*r) @ [r*8+j]
__global__ void twiddle_init(cplx* __restrict__ twA, cplx* __restrict__ twB,
                             cplx* __restrict__ twC) {
    int m = blockIdx.x * NT + threadIdx.x;
    if (m >= 4672) return;
    const float TP = -6.28318530717958647692f;
    float s, c;
    if (m < 4096) {
        int r = m >> 9, t = m & 511;
        sincosf(TP * (float)(t * r) / 4096.0f, &s, &c);
        twA[m] = mkc(c, s);
    } else if (m < 4608) {
        int k = m - 4096, r = k >> 6, j = k & 63;
        sincosf(TP * (float)(j * r) / 512.0f, &s, &c);
        twB[k] = mkc(c, s);
    } else {
        int k = m - 4608, r = k >> 3, j = k & 7;
        sincosf(TP * (float)(j * r) / 64.0f, &s, &c);
        twC[k] = mkc(c, s);
    }
}

__global__ __launch_bounds__(NT) void circconv4096_kernel(
    const float* __restrict__ A, const float* __restrict__ Bv,
    float* __restrict__ O,
    const cplx* __restrict__ twA, const cplx* __restrict__ twB,
    const cplx* __restrict__ twC)
{
    __shared__ cplx Z[SK(4095) + 1];   // 4607 cplx = 36.9 KB -> 4 blocks/CU
    const int t = threadIdx.x;
    const size_t row = blockIdx.x;
    const float* a = A + row * FFT_N;
    const float* b = Bv + row * FFT_N;
    float* o = O + row * FFT_N;

    cplx x[8];

    // ---- fwd stage 1 (stride 512): coalesced load + bf + twiddle ----
#pragma unroll
    for (int q = 0; q < 8; ++q) {
        int g = t + 512 * q;
        x[q] = mkc(a[g], b[g]);   // z = a + i*b
    }
    ip8<-1, false>(x);
#pragma unroll
    for (int m = 1; m < 8; ++m) x[m] = cmul(x[m], twA[B3(m) * 512 + t]);
#pragma unroll
    for (int m = 0; m < 8; ++m) Z[SK(t + 512 * B3(m))] = x[m];
    __syncthreads();

    // ---- stages 2..inv3 are wave-private (512-elem segments); wave fences only ----

    // ---- fwd stage 2 (stride 64) ----
    const int j2 = t & 63;
    const int base2 = ((t >> 6) << 9) + j2;
    {
#pragma unroll
        for (int q = 0; q < 8; ++q) x[q] = Z[SK(base2 + 64 * q)];
        ip8<-1, false>(x);
#pragma unroll
        for (int m = 1; m < 8; ++m) x[m] = cmul(x[m], twB[B3(m) * 64 + j2]);
        __builtin_amdgcn_wave_barrier();
#pragma unroll
        for (int m = 0; m < 8; ++m) Z[SK(base2 + 64 * B3(m))] = x[m];
    }
    __builtin_amdgcn_wave_barrier();

    // ---- fwd stage 3 (stride 8) ----
    const int j3 = t & 7;
    const int base3 = ((t >> 3) << 6) + j3;
    {
#pragma unroll
        for (int q = 0; q < 8; ++q) x[q] = Z[SK(base3 + 8 * q)];
        ip8<-1, false>(x);
#pragma unroll
        for (int m = 1; m < 8; ++m) x[m] = cmul(x[m], twC[B3(m) * 8 + j3]);
        __builtin_amdgcn_wave_barrier();
#pragma unroll
        for (int m = 0; m < 8; ++m) Z[SK(base3 + 8 * B3(m))] = x[m];
    }
    __builtin_amdgcn_wave_barrier();

    // ---- fwd stage 4 (contig) + pointwise square + inv stage 1 (contig), in regs ----
    {
        const int b4 = t * 8;
#pragma unroll
        for (int q = 0; q < 8; ++q) x[q] = Z[SK(b4 + q)];
        ip8<-1, false>(x);           // spectrum, bitrev'd within the 8
#pragma unroll
        for (int m = 0; m < 8; ++m) {
            cplx z = x[m];
            x[m] = mkc(z.x * z.x - z.y * z.y, 2.0f * z.x * z.y);  // Z^2
        }
        ip8<1, true>(x);             // consumes bitrev'd, natural out
        __builtin_amdgcn_wave_barrier();
#pragma unroll
        for (int q = 0; q < 8; ++q) Z[SK(b4 + q)] = x[q];
    }
    __builtin_amdgcn_wave_barrier();

    // ---- inv stage 2 (stride 8): conj twiddle, inverse bf ----
    {
#pragma unroll
        for (int r = 0; r < 8; ++r) x[r] = Z[SK(base3 + 8 * r)];
#pragma unroll
        for (int r = 1; r < 8; ++r) x[r] = cmulc(x[r], twC[r * 8 + j3]);
        ip8<1, false>(x);
        __builtin_amdgcn_wave_barrier();
#pragma unroll
        for (int m = 0; m < 8; ++m) Z[SK(base3 + 8 * B3(m))] = x[m];
    }
    __builtin_amdgcn_wave_barrier();

    // ---- inv stage 3 (stride 64) ----
    {
#pragma unroll
        for (int r = 0; r < 8; ++r) x[r] = Z[SK(base2 + 64 * r)];
#pragma unroll
        for (int r = 1; r < 8; ++r) x[r] = cmulc(x[r], twB[r * 64 + j2]);
        ip8<1, false>(x);
        __builtin_amdgcn_wave_barrier();
#pragma unroll
        for (int m = 0; m < 8; ++m) Z[SK(base2 + 64 * B3(m))] = x[m];
    }
    __syncthreads();   // next stage is stride-512: cross-wave

    // ---- inv stage 4 (stride 512) + coalesced store ----
    {
#pragma unroll
        for (int r = 0; r < 8; ++r) x[r] = Z[SK(t + 512 * r)];
#pragma unroll
        for (int r = 1; r < 8; ++r) x[r] = cmulc(x[r], twA[r * 512 + t]);
        ip8<1, false>(x);
        // four unnormalized inverse stages = x4096; imag-extraction trick = /2
        const float scale = 1.0f / 8192.0f;
#pragma unroll
        for (int m = 0; m < 8; ++m) o[t + 512 * B3(m)] = x[m].y * scale;
    }
}

extern "C" void kernel_launch(void* const* d_in, const int* in_sizes, int n_in,
                              void* d_out, int out_size, void* d_ws, size_t ws_size,
                              hipStream_t stream) {
    const float* a = (const float*)d_in[0];
    const float* b = (const float*)d_in[1];
    float* out = (float*)d_out;
    cplx* twA = (cplx*)d_ws;              // 4096 cplx
    cplx* twB = twA + 4096;               // 512 cplx
    cplx* twC = twB + 512;                // 64 cplx   (total 37.4 KB)
    const int B = in_sizes[0] / FFT_N;    // 8192 rows

    twiddle_init<<<10, NT, 0, stream>>>(twA, twB, twC);   // 4672 entries
    circconv4096_kernel<<<B, NT, 0, stream>>>(a, b, out, twA, twB, twC);
}

// Round 10
// 125.781 us; speedup vs baseline: 1.3417x; 1.1529x over previous
//
#include <hip/hip_runtime.h>

#define FFT_N 4096
#define NT    512
// skew: +1 cplx per 8
#define SK(i) ((i) + ((i) >> 3))
// 3-bit reverse (involution): 0,4,2,6,1,5,3,7
#define B3(m) ((((m) & 1) << 2) | ((m) & 2) | ((m) >> 2))

// complex in an even-aligned VGPR pair -> VOP3P packed f32 ops
typedef float cplx __attribute__((ext_vector_type(2)));

__device__ __forceinline__ cplx mkc(float re, float im) { cplx c; c.x = re; c.y = im; return c; }
__device__ __forceinline__ cplx cmul(cplx a, cplx b) {
    return mkc(a.x * b.x - a.y * b.y, a.x * b.y + a.y * b.x);
}
__device__ __forceinline__ cplx cmulc(cplx a, cplx b) {  // a * conj(b)
    return mkc(a.x * b.x + a.y * b.y, a.y * b.x - a.x * b.y);
}

// In-place 8-point DFT, three radix-2 layers (math verified r7-r9).
// PERMIN=false: natural in, slot m holds freq B3(m). PERMIN=true: mirrored.
template <int SGN, bool PERMIN>
__device__ __forceinline__ void ip8(cplx* x) {
    const float S = (float)SGN;
    const float R2 = 0.70710678118654752440f;
    const cplx w81 = mkc(R2, S * R2);    // W8^(S*1)
    const cplx w83 = mkc(-R2, S * R2);   // W8^(S*3)
#define BF2(i0, i1) { cplx u = x[i0], v = x[i1]; x[i0] = u + v; x[i1] = u - v; }
#define MSI(i) { cplx v = x[i]; x[i] = mkc(-S * v.y, S * v.x); }  // *= S*i
    if (!PERMIN) {
        BF2(0, 4) BF2(1, 5) BF2(2, 6) BF2(3, 7)
        x[5] = cmul(x[5], w81); MSI(6) x[7] = cmul(x[7], w83);
        BF2(0, 2) BF2(1, 3) BF2(4, 6) BF2(5, 7)
        MSI(3) MSI(7)
        BF2(0, 1) BF2(2, 3) BF2(4, 5) BF2(6, 7)
    } else {
        BF2(0, 1) BF2(2, 3) BF2(4, 5) BF2(6, 7)
        MSI(3) MSI(7)
        BF2(0, 2) BF2(1, 3) BF2(4, 6) BF2(5, 7)
        x[5] = cmul(x[5], w81); MSI(6) x[7] = cmul(x[7], w83);
        BF2(0, 4) BF2(1, 5) BF2(2, 6) BF2(3, 7)
    }
#undef BF2
#undef MSI
}

// d_ws: twA[4096]=W4096^(t*r) @ [r*512+t]; twB[512]=W512^(j*r) @ [r*64+j];
//       twC[64]=W64^(j*r) @ [r*8+j]
__global__ void twiddle_init(cplx* __restrict__ twA, cplx* __restrict__ twB,
                             cplx* __restrict__ twC) {
    int m = blockIdx.x * NT + threadIdx.x;
    if (m >= 4672) return;
    const float TP = -6.28318530717958647692f;
    float s, c;
    if (m < 4096) {
        int r = m >> 9, t = m & 511;
        sincosf(TP * (float)(t * r) / 4096.0f, &s, &c);
        twA[m] = mkc(c, s);
    } else if (m < 4608) {
        int k = m - 4096, r = k >> 6, j = k & 63;
        sincosf(TP * (float)(j * r) / 512.0f, &s, &c);
        twB[k] = mkc(c, s);
    } else {
        int k = m - 4608, r = k >> 3, j = k & 7;
        sincosf(TP * (float)(j * r) / 64.0f, &s, &c);
        twC[k] = mkc(c, s);
    }
}

__global__ __launch_bounds__(NT) void circconv4096_kernel(
    const float* __restrict__ A, const float* __restrict__ Bv,
    float* __restrict__ O,
    const cplx* __restrict__ twA, const cplx* __restrict__ twB,
    const cplx* __restrict__ twC)
{
    // two rows per block, two LDS buffers: 2 x 36.9 KB -> 2 blocks/CU
    __shared__ cplx Z0[SK(4095) + 1];
    __shared__ cplx Z1[SK(4095) + 1];
    const int t = threadIdx.x;
    const size_t r0 = (size_t)blockIdx.x * 2;
    const float* a0 = A + r0 * FFT_N;
    const float* b0 = Bv + r0 * FFT_N;
    const float* a1 = a0 + FFT_N;
    const float* b1 = b0 + FFT_N;
    float* o0 = O + r0 * FFT_N;
    float* o1 = o0 + FFT_N;

    cplx x0[8], x1[8], tw[7];

    // ---- fwd stage 1 (stride 512): both rows' loads issued up front ----
#pragma unroll
    for (int q = 0; q < 8; ++q) { int g = t + 512 * q; x0[q] = mkc(a0[g], b0[g]); }
#pragma unroll
    for (int q = 0; q < 8; ++q) { int g = t + 512 * q; x1[q] = mkc(a1[g], b1[g]); }
#pragma unroll
    for (int m = 1; m < 8; ++m) tw[m - 1] = twA[B3(m) * 512 + t];
    ip8<-1, false>(x0);
#pragma unroll
    for (int m = 1; m < 8; ++m) x0[m] = cmul(x0[m], tw[m - 1]);
#pragma unroll
    for (int m = 0; m < 8; ++m) Z0[SK(t + 512 * B3(m))] = x0[m];
    ip8<-1, false>(x1);
#pragma unroll
    for (int m = 1; m < 8; ++m) x1[m] = cmul(x1[m], tw[m - 1]);
#pragma unroll
    for (int m = 0; m < 8; ++m) Z1[SK(t + 512 * B3(m))] = x1[m];
    __syncthreads();

    // ---- middle stages: wave-private (512-elem segments), no block barriers.
    //      Per stage: issue reads for BOTH rows, then compute/write row0, row1. ----
    const int j2 = t & 63;
    const int base2 = ((t >> 6) << 9) + j2;
    const int j3 = t & 7;
    const int base3 = ((t >> 3) << 6) + j3;

    // ---- fwd stage 2 (stride 64) ----
#pragma unroll
    for (int q = 0; q < 8; ++q) x0[q] = Z0[SK(base2 + 64 * q)];
#pragma unroll
    for (int q = 0; q < 8; ++q) x1[q] = Z1[SK(base2 + 64 * q)];
#pragma unroll
    for (int m = 1; m < 8; ++m) tw[m - 1] = twB[B3(m) * 64 + j2];
    ip8<-1, false>(x0);
#pragma unroll
    for (int m = 1; m < 8; ++m) x0[m] = cmul(x0[m], tw[m - 1]);
    __builtin_amdgcn_wave_barrier();
#pragma unroll
    for (int m = 0; m < 8; ++m) Z0[SK(base2 + 64 * B3(m))] = x0[m];
    ip8<-1, false>(x1);
#pragma unroll
    for (int m = 1; m < 8; ++m) x1[m] = cmul(x1[m], tw[m - 1]);
    __builtin_amdgcn_wave_barrier();
#pragma unroll
    for (int m = 0; m < 8; ++m) Z1[SK(base2 + 64 * B3(m))] = x1[m];
    __builtin_amdgcn_wave_barrier();

    // ---- fwd stage 3 (stride 8) ----
#pragma unroll
    for (int q = 0; q < 8; ++q) x0[q] = Z0[SK(base3 + 8 * q)];
#pragma unroll
    for (int q = 0; q < 8; ++q) x1[q] = Z1[SK(base3 + 8 * q)];
#pragma unroll
    for (int m = 1; m < 8; ++m) tw[m - 1] = twC[B3(m) * 8 + j3];
    ip8<-1, false>(x0);
#pragma unroll
    for (int m = 1; m < 8; ++m) x0[m] = cmul(x0[m], tw[m - 1]);
    __builtin_amdgcn_wave_barrier();
#pragma unroll
    for (int m = 0; m < 8; ++m) Z0[SK(base3 + 8 * B3(m))] = x0[m];
    ip8<-1, false>(x1);
#pragma unroll
    for (int m = 1; m < 8; ++m) x1[m] = cmul(x1[m], tw[m - 1]);
    __builtin_amdgcn_wave_barrier();
#pragma unroll
    for (int m = 0; m < 8; ++m) Z1[SK(base3 + 8 * B3(m))] = x1[m];
    __builtin_amdgcn_wave_barrier();

    // ---- fwd stage 4 (contig) + square + inv stage 1 (contig), in registers ----
    {
        const int b4 = t * 8;
#pragma unroll
        for (int q = 0; q < 8; ++q) x0[q] = Z0[SK(b4 + q)];
#pragma unroll
        for (int q = 0; q < 8; ++q) x1[q] = Z1[SK(b4 + q)];
        ip8<-1, false>(x0);
#pragma unroll
        for (int m = 0; m < 8; ++m) {
            cplx z = x0[m];
            x0[m] = mkc(z.x * z.x - z.y * z.y, 2.0f * z.x * z.y);  // Z^2
        }
        ip8<1, true>(x0);
        __builtin_amdgcn_wave_barrier();
#pragma unroll
        for (int q = 0; q < 8; ++q) Z0[SK(b4 + q)] = x0[q];
        ip8<-1, false>(x1);
#pragma unroll
        for (int m = 0; m < 8; ++m) {
            cplx z = x1[m];
            x1[m] = mkc(z.x * z.x - z.y * z.y, 2.0f * z.x * z.y);
        }
        ip8<1, true>(x1);
        __builtin_amdgcn_wave_barrier();
#pragma unroll
        for (int q = 0; q < 8; ++q) Z1[SK(b4 + q)] = x1[q];
        __builtin_amdgcn_wave_barrier();
    }

    // ---- inv stage 2 (stride 8): conj twiddle, inverse bf ----
#pragma unroll
    for (int r = 0; r < 8; ++r) x0[r] = Z0[SK(base3 + 8 * r)];
#pragma unroll
    for (int r = 0; r < 8; ++r) x1[r] = Z1[SK(base3 + 8 * r)];
#pragma unroll
    for (int r = 1; r < 8; ++r) tw[r - 1] = twC[r * 8 + j3];
#pragma unroll
    for (int r = 1; r < 8; ++r) x0[r] = cmulc(x0[r], tw[r - 1]);
    ip8<1, false>(x0);
    __builtin_amdgcn_wave_barrier();
#pragma unroll
    for (int m = 0; m < 8; ++m) Z0[SK(base3 + 8 * B3(m))] = x0[m];
#pragma unroll
    for (int r = 1; r < 8; ++r) x1[r] = cmulc(x1[r], tw[r - 1]);
    ip8<1, false>(x1);
    __builtin_amdgcn_wave_barrier();
#pragma unroll
    for (int m = 0; m < 8; ++m) Z1[SK(base3 + 8 * B3(m))] = x1[m];
    __builtin_amdgcn_wave_barrier();

    // ---- inv stage 3 (stride 64) ----
#pragma unroll
    for (int r = 0; r < 8; ++r) x0[r] = Z0[SK(base2 + 64 * r)];
#pragma unroll
    for (int r = 0; r < 8; ++r) x1[r] = Z1[SK(base2 + 64 * r)];
#pragma unroll
    for (int r = 1; r < 8; ++r) tw[r - 1] = twB[r * 64 + j2];
#pragma unroll
    for (int r = 1; r < 8; ++r) x0[r] = cmulc(x0[r], tw[r - 1]);
    ip8<1, false>(x0);
    __builtin_amdgcn_wave_barrier();
#pragma unroll
    for (int m = 0; m < 8; ++m) Z0[SK(base2 + 64 * B3(m))] = x0[m];
#pragma unroll
    for (int r = 1; r < 8; ++r) x1[r] = cmulc(x1[r], tw[r - 1]);
    ip8<1, false>(x1);
    __builtin_amdgcn_wave_barrier();
#pragma unroll
    for (int m = 0; m < 8; ++m) Z1[SK(base2 + 64 * B3(m))] = x1[m];
    __syncthreads();   // next stage is stride-512: cross-wave

    // ---- inv stage 4 (stride 512) + coalesced store ----
    const float scale = 1.0f / 8192.0f;   // 4 unnorm inverse stages = x4096; imag trick = /2
#pragma unroll
    for (int r = 0; r < 8; ++r) x0[r] = Z0[SK(t + 512 * r)];
#pragma unroll
    for (int r = 0; r < 8; ++r) x1[r] = Z1[SK(t + 512 * r)];
#pragma unroll
    for (int r = 1; r < 8; ++r) tw[r - 1] = twA[r * 512 + t];
#pragma unroll
    for (int r = 1; r < 8; ++r) x0[r] = cmulc(x0[r], tw[r - 1]);
    ip8<1, false>(x0);
#pragma unroll
    for (int m = 0; m < 8; ++m) o0[t + 512 * B3(m)] = x0[m].y * scale;
#pragma unroll
    for (int r = 1; r < 8; ++r) x1[r] = cmulc(x1[r], tw[r - 1]);
    ip8<1, false>(x1);
#pragma unroll
    for (int m = 0; m < 8; ++m) o1[t + 512 * B3(m)] = x1[m].y * scale;
}

extern "C" void kernel_launch(void* const* d_in, const int* in_sizes, int n_in,
                              void* d_out, int out_size, void* d_ws, size_t ws_size,
                              hipStream_t stream) {
    const float* a = (const float*)d_in[0];
    const float* b = (const float*)d_in[1];
    float* out = (float*)d_out;
    cplx* twA = (cplx*)d_ws;              // 4096 cplx
    cplx* twB = twA + 4096;               // 512 cplx
    cplx* twC = twB + 512;                // 64 cplx   (total 37.4 KB)
    const int B = in_sizes[0] / FFT_N;    // 8192 rows

    twiddle_init<<<10, NT, 0, stream>>>(twA, twB, twC);   // 4672 entries
    circconv4096_kernel<<<B / 2, NT, 0, stream>>>(a, b, out, twA, twB, twC);
}

// Round 11
// 123.006 us; speedup vs baseline: 1.3720x; 1.0226x over previous
//
#include <hip/hip_runtime.h>

#define FFT_N 4096
#define NT    512
// skew: +1 unit per 8 -> all stage access patterns uniform mod 8 (conflict-free b128)
#define SK(i) ((i) + ((i) >> 3))
// 3-bit reverse (involution): 0,4,2,6,1,5,3,7
#define B3(m) ((((m) & 1) << 2) | ((m) & 2) | ((m) >> 2))

typedef float cplx  __attribute__((ext_vector_type(2)));  // (re, im), packed VOP3P math
typedef float cplx4 __attribute__((ext_vector_type(4)));  // (r0.re, r0.im, r1.re, r1.im)

__device__ __forceinline__ cplx mkc(float re, float im) { cplx c; c.x = re; c.y = im; return c; }
__device__ __forceinline__ cplx4 pack2(cplx a, cplx b) {
    cplx4 v; v.x = a.x; v.y = a.y; v.z = b.x; v.w = b.y; return v;
}
__device__ __forceinline__ cplx cmul(cplx a, cplx b) {
    return mkc(a.x * b.x - a.y * b.y, a.x * b.y + a.y * b.x);
}
__device__ __forceinline__ cplx cmulc(cplx a, cplx b) {  // a * conj(b)
    return mkc(a.x * b.x + a.y * b.y, a.y * b.x - a.x * b.y);
}

// In-place 8-point DFT, three radix-2 layers (math verified r7-r10).
// PERMIN=false: natural in, slot m holds freq B3(m). PERMIN=true: mirrored.
template <int SGN, bool PERMIN>
__device__ __forceinline__ void ip8(cplx* x) {
    const float S = (float)SGN;
    const float R2 = 0.70710678118654752440f;
    const cplx w81 = mkc(R2, S * R2);    // W8^(S*1)
    const cplx w83 = mkc(-R2, S * R2);   // W8^(S*3)
#define BF2(i0, i1) { cplx u = x[i0], v = x[i1]; x[i0] = u + v; x[i1] = u - v; }
#define MSI(i) { cplx v = x[i]; x[i] = mkc(-S * v.y, S * v.x); }  // *= S*i
    if (!PERMIN) {
        BF2(0, 4) BF2(1, 5) BF2(2, 6) BF2(3, 7)
        x[5] = cmul(x[5], w81); MSI(6) x[7] = cmul(x[7], w83);
        BF2(0, 2) BF2(1, 3) BF2(4, 6) BF2(5, 7)
        MSI(3) MSI(7)
        BF2(0, 1) BF2(2, 3) BF2(4, 5) BF2(6, 7)
    } else {
        BF2(0, 1) BF2(2, 3) BF2(4, 5) BF2(6, 7)
        MSI(3) MSI(7)
        BF2(0, 2) BF2(1, 3) BF2(4, 6) BF2(5, 7)
        x[5] = cmul(x[5], w81); MSI(6) x[7] = cmul(x[7], w83);
        BF2(0, 4) BF2(1, 5) BF2(2, 6) BF2(3, 7)
    }
#undef BF2
#undef MSI
}

// d_ws: twA[4096]=W4096^(t*r) @ [r*512+t]; twB[512]=W512^(j*r) @ [r*64+j];
//       twC[64]=W64^(j*r) @ [r*8+j]
__global__ void twiddle_init(cplx* __restrict__ twA, cplx* __restrict__ twB,
                             cplx* __restrict__ twC) {
    int m = blockIdx.x * NT + threadIdx.x;
    if (m >= 4672) return;
    const float TP = -6.28318530717958647692f;
    float s, c;
    if (m < 4096) {
        int r = m >> 9, t = m & 511;
        sincosf(TP * (float)(t * r) / 4096.0f, &s, &c);
        twA[m] = mkc(c, s);
    } else if (m < 4608) {
        int k = m - 4096, r = k >> 6, j = k & 63;
        sincosf(TP * (float)(j * r) / 512.0f, &s, &c);
        twB[k] = mkc(c, s);
    } else {
        int k = m - 4608, r = k >> 3, j = k & 7;
        sincosf(TP * (float)(j * r) / 64.0f, &s, &c);
        twC[k] = mkc(c, s);
    }
}

__global__ __launch_bounds__(NT) void circconv4096_kernel(
    const float* __restrict__ A, const float* __restrict__ Bv,
    float* __restrict__ O,
    const cplx* __restrict__ twA, const cplx* __restrict__ twB,
    const cplx* __restrict__ twC)
{
    // two rows per block, PAIRED in one b128 word per element: 73.7 KB -> 2 blocks/CU
    __shared__ cplx4 Z[SK(4095) + 1];
    const int t = threadIdx.x;
    const size_t r0 = (size_t)blockIdx.x * 2;
    const float* a0 = A + r0 * FFT_N;
    const float* b0 = Bv + r0 * FFT_N;
    const float* a1 = a0 + FFT_N;
    const float* b1 = b0 + FFT_N;
    float* o0 = O + r0 * FFT_N;
    float* o1 = o0 + FFT_N;

    cplx x0[8], x1[8], tw[7];

    // ---- fwd stage 1 (stride 512): both rows' loads issued up front ----
#pragma unroll
    for (int q = 0; q < 8; ++q) { int g = t + 512 * q; x0[q] = mkc(a0[g], b0[g]); }
#pragma unroll
    for (int q = 0; q < 8; ++q) { int g = t + 512 * q; x1[q] = mkc(a1[g], b1[g]); }
#pragma unroll
    for (int m = 1; m < 8; ++m) tw[m - 1] = twA[B3(m) * 512 + t];
    ip8<-1, false>(x0);
#pragma unroll
    for (int m = 1; m < 8; ++m) x0[m] = cmul(x0[m], tw[m - 1]);
    ip8<-1, false>(x1);
#pragma unroll
    for (int m = 1; m < 8; ++m) x1[m] = cmul(x1[m], tw[m - 1]);
#pragma unroll
    for (int m = 0; m < 8; ++m) Z[SK(t + 512 * B3(m))] = pack2(x0[m], x1[m]);
    __syncthreads();

    // ---- middle stages: wave-private (512-elem segments), wave fences only ----
    const int j2 = t & 63;
    const int base2 = ((t >> 6) << 9) + j2;
    const int j3 = t & 7;
    const int base3 = ((t >> 3) << 6) + j3;

    // ---- fwd stage 2 (stride 64) ----
#pragma unroll
    for (int q = 0; q < 8; ++q) {
        cplx4 v = Z[SK(base2 + 64 * q)];
        x0[q] = mkc(v.x, v.y); x1[q] = mkc(v.z, v.w);
    }
#pragma unroll
    for (int m = 1; m < 8; ++m) tw[m - 1] = twB[B3(m) * 64 + j2];
    ip8<-1, false>(x0);
#pragma unroll
    for (int m = 1; m < 8; ++m) x0[m] = cmul(x0[m], tw[m - 1]);
    ip8<-1, false>(x1);
#pragma unroll
    for (int m = 1; m < 8; ++m) x1[m] = cmul(x1[m], tw[m - 1]);
    __builtin_amdgcn_wave_barrier();
#pragma unroll
    for (int m = 0; m < 8; ++m) Z[SK(base2 + 64 * B3(m))] = pack2(x0[m], x1[m]);
    __builtin_amdgcn_wave_barrier();

    // ---- fwd stage 3 (stride 8) ----
#pragma unroll
    for (int q = 0; q < 8; ++q) {
        cplx4 v = Z[SK(base3 + 8 * q)];
        x0[q] = mkc(v.x, v.y); x1[q] = mkc(v.z, v.w);
    }
#pragma unroll
    for (int m = 1; m < 8; ++m) tw[m - 1] = twC[B3(m) * 8 + j3];
    ip8<-1, false>(x0);
#pragma unroll
    for (int m = 1; m < 8; ++m) x0[m] = cmul(x0[m], tw[m - 1]);
    ip8<-1, false>(x1);
#pragma unroll
    for (int m = 1; m < 8; ++m) x1[m] = cmul(x1[m], tw[m - 1]);
    __builtin_amdgcn_wave_barrier();
#pragma unroll
    for (int m = 0; m < 8; ++m) Z[SK(base3 + 8 * B3(m))] = pack2(x0[m], x1[m]);
    __builtin_amdgcn_wave_barrier();

    // ---- fwd stage 4 (contig) + square + inv stage 1 (contig), in registers ----
    {
        const int b4 = t * 8;
#pragma unroll
        for (int q = 0; q < 8; ++q) {
            cplx4 v = Z[SK(b4 + q)];
            x0[q] = mkc(v.x, v.y); x1[q] = mkc(v.z, v.w);
        }
        ip8<-1, false>(x0);
#pragma unroll
        for (int m = 0; m < 8; ++m) {
            cplx z = x0[m];
            x0[m] = mkc(z.x * z.x - z.y * z.y, 2.0f * z.x * z.y);  // Z^2
        }
        ip8<1, true>(x0);
        ip8<-1, false>(x1);
#pragma unroll
        for (int m = 0; m < 8; ++m) {
            cplx z = x1[m];
            x1[m] = mkc(z.x * z.x - z.y * z.y, 2.0f * z.x * z.y);
        }
        ip8<1, true>(x1);
        __builtin_amdgcn_wave_barrier();
#pragma unroll
        for (int q = 0; q < 8; ++q) Z[SK(b4 + q)] = pack2(x0[q], x1[q]);
        __builtin_amdgcn_wave_barrier();
    }

    // ---- inv stage 2 (stride 8): conj twiddle, inverse bf ----
#pragma unroll
    for (int r = 0; r < 8; ++r) {
        cplx4 v = Z[SK(base3 + 8 * r)];
        x0[r] = mkc(v.x, v.y); x1[r] = mkc(v.z, v.w);
    }
#pragma unroll
    for (int r = 1; r < 8; ++r) tw[r - 1] = twC[r * 8 + j3];
#pragma unroll
    for (int r = 1; r < 8; ++r) x0[r] = cmulc(x0[r], tw[r - 1]);
    ip8<1, false>(x0);
#pragma unroll
    for (int r = 1; r < 8; ++r) x1[r] = cmulc(x1[r], tw[r - 1]);
    ip8<1, false>(x1);
    __builtin_amdgcn_wave_barrier();
#pragma unroll
    for (int m = 0; m < 8; ++m) Z[SK(base3 + 8 * B3(m))] = pack2(x0[m], x1[m]);
    __builtin_amdgcn_wave_barrier();

    // ---- inv stage 3 (stride 64) ----
#pragma unroll
    for (int r = 0; r < 8; ++r) {
        cplx4 v = Z[SK(base2 + 64 * r)];
        x0[r] = mkc(v.x, v.y); x1[r] = mkc(v.z, v.w);
    }
#pragma unroll
    for (int r = 1; r < 8; ++r) tw[r - 1] = twB[r * 64 + j2];
#pragma unroll
    for (int r = 1; r < 8; ++r) x0[r] = cmulc(x0[r], tw[r - 1]);
    ip8<1, false>(x0);
#pragma unroll
    for (int r = 1; r < 8; ++r) x1[r] = cmulc(x1[r], tw[r - 1]);
    ip8<1, false>(x1);
    __builtin_amdgcn_wave_barrier();
#pragma unroll
    for (int m = 0; m < 8; ++m) Z[SK(base2 + 64 * B3(m))] = pack2(x0[m], x1[m]);
    __syncthreads();   // next stage is stride-512: cross-wave

    // ---- inv stage 4 (stride 512) + coalesced store ----
    const float scale = 1.0f / 8192.0f;   // 4 unnorm inverse stages = x4096; imag trick = /2
#pragma unroll
    for (int r = 0; r < 8; ++r) {
        cplx4 v = Z[SK(t + 512 * r)];
        x0[r] = mkc(v.x, v.y); x1[r] = mkc(v.z, v.w);
    }
#pragma unroll
    for (int r = 1; r < 8; ++r) tw[r - 1] = twA[r * 512 + t];
#pragma unroll
    for (int r = 1; r < 8; ++r) x0[r] = cmulc(x0[r], tw[r - 1]);
    ip8<1, false>(x0);
#pragma unroll
    for (int m = 0; m < 8; ++m) o0[t + 512 * B3(m)] = x0[m].y * scale;
#pragma unroll
    for (int r = 1; r < 8; ++r) x1[r] = cmulc(x1[r], tw[r - 1]);
    ip8<1, false>(x1);
#pragma unroll
    for (int m = 0; m < 8; ++m) o1[t + 512 * B3(m)] = x1[m].y * scale;
}

extern "C" void kernel_launch(void* const* d_in, const int* in_sizes, int n_in,
                              void* d_out, int out_size, void* d_ws, size_t ws_size,
                              hipStream_t stream) {
    const float* a = (const float*)d_in[0];
    const float* b = (const float*)d_in[1];
    float* out = (float*)d_out;
    cplx* twA = (cplx*)d_ws;              // 4096 cplx
    cplx* twB = twA + 4096;               // 512 cplx
    cplx* twC = twB + 512;                // 64 cplx   (total 37.4 KB)
    const int B = in_sizes[0] / FFT_N;    // 8192 rows

    twiddle_init<<<10, NT, 0, stream>>>(twA, twB, twC);   // 4672 entries
    circconv4096_kernel<<<B / 2, NT, 0, stream>>>(a, b, out, twA, twB, twC);
}

// Round 12
// 120.977 us; speedup vs baseline: 1.3950x; 1.0168x over previous
//
#include <hip/hip_runtime.h>

#define FFT_N 4096
#define NT    256
// skew for 256-thread radix-16 layout: +1 unit per 16.
// Verified uniform mod 8 (conflict-free b128) for all three stage patterns:
//  contig (17t+q), stride-16 (j+q mod 8), stride-256 (t+(t>>4) mod 8).
#define SK(i) ((i) + ((i) >> 4))
// base-4 digit-reverse involution for 16: P(m) = ((m&3)<<2)|(m>>2)
#define PM(m) ((((m) & 3) << 2) | ((m) >> 2))

typedef float cplx  __attribute__((ext_vector_type(2)));  // (re, im), packed math
typedef float cplx4 __attribute__((ext_vector_type(4)));  // (r0.re, r0.im, r1.re, r1.im)

__device__ __forceinline__ cplx mkc(float re, float im) { cplx c; c.x = re; c.y = im; return c; }
__device__ __forceinline__ cplx4 pack2(cplx a, cplx b) {
    cplx4 v; v.x = a.x; v.y = a.y; v.z = b.x; v.w = b.y; return v;
}
__device__ __forceinline__ cplx cmul(cplx a, cplx b) {
    return mkc(a.x * b.x - a.y * b.y, a.x * b.y + a.y * b.x);
}
__device__ __forceinline__ cplx cmulc(cplx a, cplx b) {  // a * conj(b)
    return mkc(a.x * b.x + a.y * b.y, a.y * b.x - a.x * b.y);
}

// In-place 16-point DFT via two radix-4 layers (math verified r6).
// PERMIN=false: natural in, slot m holds freq PM(m). PERMIN=true: mirrored.
template <int SGN, bool PERMIN>
__device__ __forceinline__ void ip16(cplx* x) {
    const float S = (float)SGN;
    const float C1 = 0.92387953251128675613f;   // cos(pi/8)
    const float S1 = 0.38268343236508977173f;   // sin(pi/8)
    const float R2 = 0.70710678118654752440f;   // sqrt(2)/2
#define BF4(i0, i1, i2, i3) do { \
        cplx x0 = x[i0], x1 = x[i1], x2 = x[i2], x3 = x[i3]; \
        cplx t0 = x0 + x2, t1 = x0 - x2; \
        cplx t2 = x1 + x3, t3 = x1 - x3; \
        cplx it3 = mkc(-S * t3.y, S * t3.x); \
        x[i0] = t0 + t2; x[i1] = t1 + it3; \
        x[i2] = t0 - t2; x[i3] = t1 - it3; \
    } while (0)
    if (!PERMIN) { BF4(0, 4, 8, 12); BF4(1, 5, 9, 13); BF4(2, 6, 10, 14); BF4(3, 7, 11, 15); }
    else         { BF4(0, 1, 2, 3);  BF4(4, 5, 6, 7);  BF4(8, 9, 10, 11); BF4(12, 13, 14, 15); }
    // mid twiddles: slot m *= W16^(S * (m&3) * (m>>2))
    const cplx w1 = mkc(C1, S * S1), w2 = mkc(R2, S * R2), w3 = mkc(S1, S * C1);
    const cplx w6 = mkc(-R2, S * R2), w9 = mkc(-C1, -S * S1);
    x[5]  = cmul(x[5],  w1);
    x[6]  = cmul(x[6],  w2);
    x[7]  = cmul(x[7],  w3);
    x[9]  = cmul(x[9],  w2);
    { cplx v = x[10]; x[10] = mkc(-S * v.y, S * v.x); }  // w4 = S*i
    x[11] = cmul(x[11], w6);
    x[13] = cmul(x[13], w3);
    x[14] = cmul(x[14], w6);
    x[15] = cmul(x[15], w9);
    if (!PERMIN) { BF4(0, 1, 2, 3);  BF4(4, 5, 6, 7);  BF4(8, 9, 10, 11); BF4(12, 13, 14, 15); }
    else         { BF4(0, 4, 8, 12); BF4(1, 5, 9, 13); BF4(2, 6, 10, 14); BF4(3, 7, 11, 15); }
#undef BF4
}

// d_ws: twA[4096] = W4096^(t*r) at [r*256+t]; twB[256] = W256^(j*r) at [r*16+j]
__global__ void twiddle_init(cplx* __restrict__ twA, cplx* __restrict__ twB) {
    int m = blockIdx.x * NT + threadIdx.x;   // 0..4351
    if (m >= 4352) return;
    float s, c;
    if (m < 4096) {
        int r = m >> 8, t = m & 255;
        sincosf(-6.28318530717958647692f * (float)(t * r) / 4096.0f, &s, &c);
        twA[m] = mkc(c, s);
    } else {
        int k = m - 4096;                    // k = r*16 + j
        int r = k >> 4, j = k & 15;
        sincosf(-6.28318530717958647692f * (float)(j * r) / 256.0f, &s, &c);
        twB[k] = mkc(c, s);
    }
}

__global__ __launch_bounds__(NT) void circconv4096_kernel(
    const float* __restrict__ A, const float* __restrict__ Bv,
    float* __restrict__ O,
    const cplx* __restrict__ twA, const cplx* __restrict__ twB)
{
    // two rows per block, paired per-element in one b128: 69.6 KB -> 2 blocks/CU
    __shared__ cplx4 Z[SK(4095) + 1];
    const int t = threadIdx.x;
    const size_t r0 = (size_t)blockIdx.x * 2;
    const float* a0 = A + r0 * FFT_N;
    const float* b0 = Bv + r0 * FFT_N;
    const float* a1 = a0 + FFT_N;
    const float* b1 = b0 + FFT_N;
    float* o0 = O + r0 * FFT_N;
    float* o1 = o0 + FFT_N;

    cplx x0[16], x1[16];

    // ---- fwd stage 1 (stride 256): coalesced loads, both rows ----
#pragma unroll
    for (int q = 0; q < 16; ++q) { int g = t + 256 * q; x0[q] = mkc(a0[g], b0[g]); }
#pragma unroll
    for (int q = 0; q < 16; ++q) { int g = t + 256 * q; x1[q] = mkc(a1[g], b1[g]); }
    ip16<-1, false>(x0);
    ip16<-1, false>(x1);
#pragma unroll
    for (int m = 1; m < 16; ++m) {
        cplx w = twA[PM(m) * 256 + t];
        x0[m] = cmul(x0[m], w);
        x1[m] = cmul(x1[m], w);
    }
#pragma unroll
    for (int m = 0; m < 16; ++m) Z[SK(t + 256 * PM(m))] = pack2(x0[m], x1[m]);
    __syncthreads();

    // ---- middle stages wave-private: wave w owns elements [1024w, 1024w+1024) ----
    const int j = t & 15;
    const int base = ((t >> 4) << 8) + j;

    // ---- fwd stage 2 (stride 16) ----
#pragma unroll
    for (int q = 0; q < 16; ++q) {
        cplx4 v = Z[SK(base + 16 * q)];
        x0[q] = mkc(v.x, v.y); x1[q] = mkc(v.z, v.w);
    }
    ip16<-1, false>(x0);
    ip16<-1, false>(x1);
#pragma unroll
    for (int m = 1; m < 16; ++m) {
        cplx w = twB[PM(m) * 16 + j];
        x0[m] = cmul(x0[m], w);
        x1[m] = cmul(x1[m], w);
    }
    __builtin_amdgcn_wave_barrier();
#pragma unroll
    for (int m = 0; m < 16; ++m) Z[SK(base + 16 * PM(m))] = pack2(x0[m], x1[m]);
    __builtin_amdgcn_wave_barrier();

    // ---- fwd stage 3 (contig) + pointwise square + inv stage 1 (contig) ----
    {
        const int b3 = t * 16;
#pragma unroll
        for (int q = 0; q < 16; ++q) {
            cplx4 v = Z[SK(b3 + q)];
            x0[q] = mkc(v.x, v.y); x1[q] = mkc(v.z, v.w);
        }
        ip16<-1, false>(x0);
#pragma unroll
        for (int m = 0; m < 16; ++m) {
            cplx z = x0[m];
            x0[m] = mkc(z.x * z.x - z.y * z.y, 2.0f * z.x * z.y);  // Z^2
        }
        ip16<1, true>(x0);
        ip16<-1, false>(x1);
#pragma unroll
        for (int m = 0; m < 16; ++m) {
            cplx z = x1[m];
            x1[m] = mkc(z.x * z.x - z.y * z.y, 2.0f * z.x * z.y);
        }
        ip16<1, true>(x1);
        __builtin_amdgcn_wave_barrier();
#pragma unroll
        for (int q = 0; q < 16; ++q) Z[SK(b3 + q)] = pack2(x0[q], x1[q]);
        __builtin_amdgcn_wave_barrier();
    }

    // ---- inv stage 2 (stride 16): conj twiddle, inverse dft ----
#pragma unroll
    for (int r = 0; r < 16; ++r) {
        cplx4 v = Z[SK(base + 16 * r)];
        x0[r] = mkc(v.x, v.y); x1[r] = mkc(v.z, v.w);
    }
#pragma unroll
    for (int r = 1; r < 16; ++r) {
        cplx w = twB[r * 16 + j];
        x0[r] = cmulc(x0[r], w);
        x1[r] = cmulc(x1[r], w);
    }
    ip16<1, false>(x0);
    ip16<1, false>(x1);
    __builtin_amdgcn_wave_barrier();
#pragma unroll
    for (int m = 0; m < 16; ++m) Z[SK(base + 16 * PM(m))] = pack2(x0[m], x1[m]);
    __syncthreads();   // next stage is stride-256: cross-wave

    // ---- inv stage 3 (stride 256) + coalesced store ----
    const float scale = 1.0f / 8192.0f;  // 3 unnorm inverse ip16 = x4096; imag trick = /2
#pragma unroll
    for (int r = 0; r < 16; ++r) {
        cplx4 v = Z[SK(t + 256 * r)];
        x0[r] = mkc(v.x, v.y); x1[r] = mkc(v.z, v.w);
    }
#pragma unroll
    for (int r = 1; r < 16; ++r) {
        cplx w = twA[r * 256 + t];
        x0[r] = cmulc(x0[r], w);
        x1[r] = cmulc(x1[r], w);
    }
    ip16<1, false>(x0);
#pragma unroll
    for (int m = 0; m < 16; ++m) o0[t + 256 * PM(m)] = x0[m].y * scale;
    ip16<1, false>(x1);
#pragma unroll
    for (int m = 0; m < 16; ++m) o1[t + 256 * PM(m)] = x1[m].y * scale;
}

extern "C" void kernel_launch(void* const* d_in, const int* in_sizes, int n_in,
                              void* d_out, int out_size, void* d_ws, size_t ws_size,
                              hipStream_t stream) {
    const float* a = (const float*)d_in[0];
    const float* b = (const float*)d_in[1];
    float* out = (float*)d_out;
    cplx* twA = (cplx*)d_ws;              // 4096 cplx
    cplx* twB = twA + 4096;               // 256 cplx  (total 34 KB)
    const int B = in_sizes[0] / FFT_N;    // 8192 rows

    twiddle_init<<<17, NT, 0, stream>>>(twA, twB);        // 4352 entries
    circconv4096_kernel<<<B / 2, NT, 0, stream>>>(a, b, out, twA, twB);
}

// Round 13
// 119.729 us; speedup vs baseline: 1.4096x; 1.0104x over previous
//
#include <hip/hip_runtime.h>

#define FFT_N 4096
#define NT    256
// skew in 8-byte units: +1 per 16; all stage patterns conflict-free for b64
#define SK(i) ((i) + ((i) >> 4))
// base-4 digit-reverse involution for 16: P(m) = ((m&3)<<2)|(m>>2)
#define PM(m) ((((m) & 3) << 2) | ((m) >> 2))

typedef float    cplx __attribute__((ext_vector_type(2)));  // (re, im) fp32 math
typedef _Float16 h4   __attribute__((ext_vector_type(4)));  // LDS: r0.re,r0.im,r1.re,r1.im

__device__ __forceinline__ cplx mkc(float re, float im) { cplx c; c.x = re; c.y = im; return c; }
__device__ __forceinline__ h4 packh(cplx a, cplx b) {
    h4 v; v.x = (_Float16)a.x; v.y = (_Float16)a.y; v.z = (_Float16)b.x; v.w = (_Float16)b.y;
    return v;
}
__device__ __forceinline__ cplx cmul(cplx a, cplx b) {
    return mkc(a.x * b.x - a.y * b.y, a.x * b.y + a.y * b.x);
}
__device__ __forceinline__ cplx cmulc(cplx a, cplx b) {  // a * conj(b)
    return mkc(a.x * b.x + a.y * b.y, a.y * b.x - a.x * b.y);
}

// In-place 16-point DFT via two radix-4 layers (math verified r6/r12).
// PERMIN=false: natural in, slot m holds freq PM(m). PERMIN=true: mirrored.
template <int SGN, bool PERMIN>
__device__ __forceinline__ void ip16(cplx* x) {
    const float S = (float)SGN;
    const float C1 = 0.92387953251128675613f;   // cos(pi/8)
    const float S1 = 0.38268343236508977173f;   // sin(pi/8)
    const float R2 = 0.70710678118654752440f;   // sqrt(2)/2
#define BF4(i0, i1, i2, i3) do { \
        cplx x0 = x[i0], x1 = x[i1], x2 = x[i2], x3 = x[i3]; \
        cplx t0 = x0 + x2, t1 = x0 - x2; \
        cplx t2 = x1 + x3, t3 = x1 - x3; \
        cplx it3 = mkc(-S * t3.y, S * t3.x); \
        x[i0] = t0 + t2; x[i1] = t1 + it3; \
        x[i2] = t0 - t2; x[i3] = t1 - it3; \
    } while (0)
    if (!PERMIN) { BF4(0, 4, 8, 12); BF4(1, 5, 9, 13); BF4(2, 6, 10, 14); BF4(3, 7, 11, 15); }
    else         { BF4(0, 1, 2, 3);  BF4(4, 5, 6, 7);  BF4(8, 9, 10, 11); BF4(12, 13, 14, 15); }
    const cplx w1 = mkc(C1, S * S1), w2 = mkc(R2, S * R2), w3 = mkc(S1, S * C1);
    const cplx w6 = mkc(-R2, S * R2), w9 = mkc(-C1, -S * S1);
    x[5]  = cmul(x[5],  w1);
    x[6]  = cmul(x[6],  w2);
    x[7]  = cmul(x[7],  w3);
    x[9]  = cmul(x[9],  w2);
    { cplx v = x[10]; x[10] = mkc(-S * v.y, S * v.x); }  // w4 = S*i
    x[11] = cmul(x[11], w6);
    x[13] = cmul(x[13], w3);
    x[14] = cmul(x[14], w6);
    x[15] = cmul(x[15], w9);
    if (!PERMIN) { BF4(0, 1, 2, 3);  BF4(4, 5, 6, 7);  BF4(8, 9, 10, 11); BF4(12, 13, 14, 15); }
    else         { BF4(0, 4, 8, 12); BF4(1, 5, 9, 13); BF4(2, 6, 10, 14); BF4(3, 7, 11, 15); }
#undef BF4
}

// d_ws: twA[4096] = W4096^(t*r) at [r*256+t]; twB[256] = W256^(j*r) at [r*16+j]
__global__ void twiddle_init(cplx* __restrict__ twA, cplx* __restrict__ twB) {
    int m = blockIdx.x * NT + threadIdx.x;   // 0..4351
    if (m >= 4352) return;
    float s, c;
    if (m < 4096) {
        int r = m >> 8, t = m & 255;
        sincosf(-6.28318530717958647692f * (float)(t * r) / 4096.0f, &s, &c);
        twA[m] = mkc(c, s);
    } else {
        int k = m - 4096;                    // k = r*16 + j
        int r = k >> 4, j = k & 15;
        sincosf(-6.28318530717958647692f * (float)(j * r) / 256.0f, &s, &c);
        twB[k] = mkc(c, s);
    }
}

__global__ __launch_bounds__(NT) void circconv4096_kernel(
    const float* __restrict__ A, const float* __restrict__ Bv,
    float* __restrict__ O,
    const cplx* __restrict__ twA, const cplx* __restrict__ twB)
{
    // two rows per block, paired per-element as 4xf16 (8 B): 34.8 KB -> 4 blocks/CU
    __shared__ h4 Z[SK(4095) + 1];
    const int t = threadIdx.x;
    const size_t r0 = (size_t)blockIdx.x * 2;
    const float* a0 = A + r0 * FFT_N;
    const float* b0 = Bv + r0 * FFT_N;
    const float* a1 = a0 + FFT_N;
    const float* b1 = b0 + FFT_N;
    float* o0 = O + r0 * FFT_N;
    float* o1 = o0 + FFT_N;

    cplx x0[16], x1[16];

    // ---- fwd stage 1 (stride 256): coalesced loads, both rows ----
#pragma unroll
    for (int q = 0; q < 16; ++q) { int g = t + 256 * q; x0[q] = mkc(a0[g], b0[g]); }
#pragma unroll
    for (int q = 0; q < 16; ++q) { int g = t + 256 * q; x1[q] = mkc(a1[g], b1[g]); }
    ip16<-1, false>(x0);
    ip16<-1, false>(x1);
#pragma unroll
    for (int m = 1; m < 16; ++m) {
        cplx w = twA[PM(m) * 256 + t];
        x0[m] = cmul(x0[m], w);
        x1[m] = cmul(x1[m], w);
    }
#pragma unroll
    for (int m = 0; m < 16; ++m) Z[SK(t + 256 * PM(m))] = packh(x0[m], x1[m]);
    __syncthreads();

    // ---- middle stages wave-private: wave w owns elements [1024w, 1024w+1024) ----
    const int j = t & 15;
    const int base = ((t >> 4) << 8) + j;

    // ---- fwd stage 2 (stride 16) ----
#pragma unroll
    for (int q = 0; q < 16; ++q) {
        h4 v = Z[SK(base + 16 * q)];
        x0[q] = mkc((float)v.x, (float)v.y); x1[q] = mkc((float)v.z, (float)v.w);
    }
    ip16<-1, false>(x0);
    ip16<-1, false>(x1);
#pragma unroll
    for (int m = 1; m < 16; ++m) {
        cplx w = twB[PM(m) * 16 + j];
        x0[m] = cmul(x0[m], w);
        x1[m] = cmul(x1[m], w);
    }
    __builtin_amdgcn_wave_barrier();
#pragma unroll
    for (int m = 0; m < 16; ++m) Z[SK(base + 16 * PM(m))] = packh(x0[m], x1[m]);
    __builtin_amdgcn_wave_barrier();

    // ---- fwd stage 3 (contig) + scaled square + inv stage 1 (contig) ----
    {
        const int b3 = t * 16;
        const float s = 1.0f / 8192.0f;   // fold /4096 (ifft) and /2 (imag trick) HERE
#pragma unroll
        for (int q = 0; q < 16; ++q) {
            h4 v = Z[SK(b3 + q)];
            x0[q] = mkc((float)v.x, (float)v.y); x1[q] = mkc((float)v.z, (float)v.w);
        }
        ip16<-1, false>(x0);
#pragma unroll
        for (int m = 0; m < 16; ++m) {
            cplx z = x0[m];
            x0[m] = mkc((z.x * z.x - z.y * z.y) * s, 2.0f * s * z.x * z.y);
        }
        ip16<1, true>(x0);
        ip16<-1, false>(x1);
#pragma unroll
        for (int m = 0; m < 16; ++m) {
            cplx z = x1[m];
            x1[m] = mkc((z.x * z.x - z.y * z.y) * s, 2.0f * s * z.x * z.y);
        }
        ip16<1, true>(x1);
        __builtin_amdgcn_wave_barrier();
#pragma unroll
        for (int q = 0; q < 16; ++q) Z[SK(b3 + q)] = packh(x0[q], x1[q]);
        __builtin_amdgcn_wave_barrier();
    }

    // ---- inv stage 2 (stride 16): conj twiddle, inverse dft ----
#pragma unroll
    for (int r = 0; r < 16; ++r) {
        h4 v = Z[SK(base + 16 * r)];
        x0[r] = mkc((float)v.x, (float)v.y); x1[r] = mkc((float)v.z, (float)v.w);
    }
#pragma unroll
    for (int r = 1; r < 16; ++r) {
        cplx w = twB[r * 16 + j];
        x0[r] = cmulc(x0[r], w);
        x1[r] = cmulc(x1[r], w);
    }
    ip16<1, false>(x0);
    ip16<1, false>(x1);
    __builtin_amdgcn_wave_barrier();
#pragma unroll
    for (int m = 0; m < 16; ++m) Z[SK(base + 16 * PM(m))] = packh(x0[m], x1[m]);
    __syncthreads();   // next stage is stride-256: cross-wave

    // ---- inv stage 3 (stride 256) + coalesced store (normalization already folded) ----
#pragma unroll
    for (int r = 0; r < 16; ++r) {
        h4 v = Z[SK(t + 256 * r)];
        x0[r] = mkc((float)v.x, (float)v.y); x1[r] = mkc((float)v.z, (float)v.w);
    }
#pragma unroll
    for (int r = 1; r < 16; ++r) {
        cplx w = twA[r * 256 + t];
        x0[r] = cmulc(x0[r], w);
        x1[r] = cmulc(x1[r], w);
    }
    ip16<1, false>(x0);
#pragma unroll
    for (int m = 0; m < 16; ++m) o0[t + 256 * PM(m)] = x0[m].y;
    ip16<1, false>(x1);
#pragma unroll
    for (int m = 0; m < 16; ++m) o1[t + 256 * PM(m)] = x1[m].y;
}

extern "C" void kernel_launch(void* const* d_in, const int* in_sizes, int n_in,
                              void* d_out, int out_size, void* d_ws, size_t ws_size,
                              hipStream_t stream) {
    const float* a = (const float*)d_in[0];
    const float* b = (const float*)d_in[1];
    float* out = (float*)d_out;
    cplx* twA = (cplx*)d_ws;              // 4096 cplx
    cplx* twB = twA + 4096;               // 256 cplx  (total 34 KB)
    const int B = in_sizes[0] / FFT_N;    // 8192 rows

    twiddle_init<<<17, NT, 0, stream>>>(twA, twB);        // 4352 entries
    circconv4096_kernel<<<B / 2, NT, 0, stream>>>(a, b, out, twA, twB);
}